// Round 8
// baseline (28.452 us; speedup 1.0000x reference)
//
#include <hip/hip_runtime.h>

typedef float v4f __attribute__((ext_vector_type(4)));

#define LPTS 2048
#define BIGV 1e12f

// f(r) = WALL * softplus((4-r)/0.2); smoothstep dropped (f<=2e-8 where sw<1).
// softplus in log2 domain: ln2 * log2(1 + exp2(28.8539008 - 7.2134752*r)).
// Triangle counted once -> final scale 2 * WALL * ln2 = 13.86294361.

__device__ __forceinline__ float pterm(float d2) {
    const float r = __builtin_amdgcn_sqrtf(d2);
    const float e = __builtin_amdgcn_exp2f(fmaf(r, -7.2134752f, 28.8539008f));
    return __builtin_amdgcn_logf(1.0f + e);   // v_log_f32 == log2; ~0 for far pairs
}

// Row i vs j in [j0, 2047]; 4 consecutive j per lane, anchored at the top so all
// ds_read_b128 stay 16B-aligned. j0 is wave-uniform.
__device__ __forceinline__ float row_seg4(const float* __restrict__ s, int j0, int lane,
                                          float xi, float yi, float zi) {
    const int n     = 2048 - j0;     // uniform
    const int fullc = n >> 8;        // unmasked 256-pair chunks
    const int rem   = n & 255;
    const int base  = 2044 - 4 * lane;   // multiple of 4 -> 16B aligned
    float acc = 0.0f;

    for (int c = 0; c < fullc; ++c) {
        const int jb = base - 256 * c;                    // >= j0 + rem
        const v4f xv = *(const v4f*)(s + jb);             // ds_read_b128
        const v4f yv = *(const v4f*)(s + LPTS + jb);
        const v4f zv = *(const v4f*)(s + 2 * LPTS + jb);
        const v4f dx = xv - xi, dy = yv - yi, dz = zv - zi;
        v4f d2 = dx * dx;
        d2 = __builtin_elementwise_fma(dy, dy, d2);
        d2 = __builtin_elementwise_fma(dz, dz, d2);
        acc += pterm(d2.x); acc += pterm(d2.y);
        acc += pterm(d2.z); acc += pterm(d2.w);
    }
    if (rem) {                                            // single masked boundary chunk
        const int jbu = base - 256 * fullc;               // may be < j0, even < 0
        const int jcl = (jbu > 0) ? jbu : 0;              // clamp (stays 16B aligned)
        const v4f xv = *(const v4f*)(s + jcl);
        const v4f yv = *(const v4f*)(s + LPTS + jcl);
        const v4f zv = *(const v4f*)(s + 2 * LPTS + jcl);
        const v4f dx = xv - xi, dy = yv - yi, dz = zv - zi;
        v4f d2 = dx * dx;
        d2 = __builtin_elementwise_fma(dy, dy, d2);
        d2 = __builtin_elementwise_fma(dz, dz, d2);
        acc += pterm((jbu     >= j0) ? d2.x : BIGV);
        acc += pterm((jbu + 1 >= j0) ? d2.y : BIGV);
        acc += pterm((jbu + 2 >= j0) ? d2.z : BIGV);
        acc += pterm((jbu + 3 >= j0) ? d2.w : BIGV);
    }
    return acc;
}

__global__ __launch_bounds__(512, 8) void pair_energy_kernel(const float* __restrict__ R,
                                                             float* __restrict__ ws,
                                                             unsigned* __restrict__ cnt,
                                                             float* __restrict__ out,
                                                             int nblk_per_batch) {
    __shared__ float lds[3 * LPTS];              // SoA x|y|z, 24 KB
    __shared__ float sp[8];

    const int t    = threadIdx.x;
    const int wave = t >> 6;
    const int lane = t & 63;
    const int lb   = blockIdx.x & 31;            // 32 blocks per batch
    const int bb   = blockIdx.x >> 5;
    const float* Rb = R + (size_t)bb * (LPTS * 3);

    // stage: 3 coalesced float4 loads per thread, repacked AoS->SoA
    #pragma unroll
    for (int k = 0; k < 3; ++k) {
        const int f4 = t + 512 * k;
        const float4 v = ((const float4*)Rb)[f4];
        #pragma unroll
        for (int c = 0; c < 4; ++c) {
            const unsigned f = 4u * (unsigned)f4 + c;
            const unsigned p = f / 3u;           // magic-mul div
            const unsigned comp = f - 3u * p;
            lds[comp * LPTS + p] = ((const float*)&v)[c];
        }
    }
    __syncthreads();

    // 4 unit-rounds per wave; unit u pairs row A (i=u) with row B (i=2045-u)
    float acc = 0.0f;
    for (int k = 0; k < 4; ++k) {
        const int u = __builtin_amdgcn_readfirstlane(k * 256 + lb * 8 + wave);
        if (u < 1023) {                          // u==1023 is a no-op unit
            const int iB = 2045 - u;
            acc += row_seg4(lds, u + 2, lane,
                            lds[u],  lds[LPTS + u],  lds[2 * LPTS + u]);
            acc += row_seg4(lds, 2047 - u, lane,
                            lds[iB], lds[LPTS + iB], lds[2 * LPTS + iB]);
        }
    }

    #pragma unroll
    for (int off = 32; off > 0; off >>= 1) acc += __shfl_xor(acc, off, 64);
    if (lane == 0) sp[wave] = acc;
    __syncthreads();

    if (t == 0) {
        float partial = sp[0];
        #pragma unroll
        for (int w = 1; w < 8; ++w) partial += sp[w];
        ws[blockIdx.x] = partial;                // plain store, then release fence
        __threadfence();                         // device-scope: push partial out
        const unsigned old = atomicAdd(&cnt[bb], 1u);
        if (old == (unsigned)(nblk_per_batch - 1)) {
            __threadfence();                     // acquire: invalidate stale caches
            volatile const float* wv = ws + bb * nblk_per_batch;
            float s = 0.0f;
            #pragma unroll
            for (int q = 0; q < 32; ++q) s += wv[q];   // fixed order: deterministic
            out[bb] = s * 13.86294361f;          // 2 * WALL * ln2
        }
    }
}

extern "C" void kernel_launch(void* const* d_in, const int* in_sizes, int n_in,
                              void* d_out, int out_size, void* d_ws, size_t ws_size,
                              hipStream_t stream) {
    (void)n_in; (void)out_size; (void)ws_size;
    const float* R = (const float*)d_in[0];
    float* out = (float*)d_out;
    float* ws  = (float*)d_ws;

    const int B = in_sizes[0] / (LPTS * 3);
    const int nblk = B * 32;                       // 32 blocks per batch
    unsigned* cnt = (unsigned*)(ws + nblk);        // counters after partials

    (void)hipMemsetAsync(cnt, 0, (size_t)B * sizeof(unsigned), stream);
    pair_energy_kernel<<<nblk, 512, 0, stream>>>(R, ws, cnt, out, 32);
}